// Round 1
// baseline (178.459 us; speedup 1.0000x reference)
//
#include <hip/hip_runtime.h>
#include <hip/hip_bf16.h>

#define N_IN   5023
#define B_SZ   64
#define H_DIM  256
#define NPAD   5120
#define NOUT3  192        // B_SZ * 3
#define OUT_ELEMS (B_SZ * N_IN * 3)   // 964416

typedef short bf16x8 __attribute__((ext_vector_type(8)));
typedef float f32x4  __attribute__((ext_vector_type(4)));

__device__ inline void async_copy16(const void* g, void* l) {
    __builtin_amdgcn_global_load_lds(
        (const __attribute__((address_space(1))) unsigned int*)g,
        (__attribute__((address_space(3))) unsigned int*)l,
        16, 0, 0);
}

// ---- zero init: out (964416 f32) and l1 (5120 f32) ----
__global__ void zero_kernel(float* __restrict__ out, float* __restrict__ l1) {
    int idx = blockIdx.x * 256 + threadIdx.x;
    if (idx < NPAD) l1[idx] = 0.0f;
    if (idx < OUT_ELEMS) out[idx] = 0.0f;
}

// ---- key_w (5023x256 f32) -> keyb bf16 padded [5120][256] ----
__global__ void conv_key(const float* __restrict__ kw, short* __restrict__ keyb) {
    int idx = blockIdx.x * 256 + threadIdx.x;     // i*256 + h
    if (idx >= NPAD * H_DIM) return;
    int i = idx >> 8, h = idx & 255;
    float v = (i < N_IN) ? kw[(size_t)i * H_DIM + h] : 0.0f;
    ((__hip_bfloat16*)keyb)[idx] = __float2bfloat16(v);
}

// ---- query_w (256x5023 f32) -> qt bf16 padded [5120][256], transposed, *1/16 ----
__global__ void conv_qt(const float* __restrict__ qw, short* __restrict__ qtb) {
    int idx = blockIdx.x * 256 + threadIdx.x;     // o*256 + h
    if (idx >= NPAD * H_DIM) return;
    int o = idx >> 8, h = idx & 255;
    float v = (o < N_IN) ? qw[(size_t)h * N_IN + o] * 0.0625f : 0.0f;
    ((__hip_bfloat16*)qtb)[idx] = __float2bfloat16(v);
}

// ---- GEMM1: score_t[o][i] = sum_h qt[o][h]*key[i][h]; also l1[i] += sum_o |.| ----
// M = N = 5120 (padded), K = 256. Tile 128x128, BK=64, 4 waves (2x2), wave tile 64x64.
__launch_bounds__(256)
__global__ void gemm1(const short* __restrict__ qt, const short* __restrict__ keyb,
                      short* __restrict__ scoreT, float* __restrict__ l1) {
    __shared__ short As[128 * 64];
    __shared__ short Bs[128 * 64];
    const int bm = blockIdx.x, bn = blockIdx.y;
    const int tid = threadIdx.x, lane = tid & 63, wid = tid >> 6;
    const int wave_m = wid >> 1, wave_n = wid & 1;
    const int srow = lane >> 3;            // row within 8-row chunk
    const int scol = (lane & 7) * 8;       // bf16 col offset (8 bf16 = 16B)

    f32x4 acc[4][4];
    const f32x4 zf = {0.f, 0.f, 0.f, 0.f};
    for (int a = 0; a < 4; ++a)
        for (int b = 0; b < 4; ++b) acc[a][b] = zf;

    for (int kb = 0; kb < H_DIM; kb += 64) {
        __syncthreads();
        for (int c = 0; c < 4; ++c) {
            int q = wid * 4 + c;               // 1KB chunk id, 0..15
            int row = q * 8 + srow;
            async_copy16(qt   + (size_t)(bm * 128 + row) * H_DIM + kb + scol, As + q * 512);
            async_copy16(keyb + (size_t)(bn * 128 + row) * H_DIM + kb + scol, Bs + q * 512);
        }
        __syncthreads();
        for (int kk = 0; kk < 64; kk += 32) {
            bf16x8 af[4], bf[4];
            int ko = kk + (lane >> 4) * 8;
            for (int t = 0; t < 4; ++t) {
                af[t] = *(const bf16x8*)(As + (wave_m * 64 + t * 16 + (lane & 15)) * 64 + ko);
                bf[t] = *(const bf16x8*)(Bs + (wave_n * 64 + t * 16 + (lane & 15)) * 64 + ko);
            }
            for (int tm = 0; tm < 4; ++tm)
                for (int tn = 0; tn < 4; ++tn)
                    acc[tm][tn] = __builtin_amdgcn_mfma_f32_16x16x32_bf16(
                        af[tm], bf[tn], acc[tm][tn], 0, 0, 0);
        }
    }

    const int quad = lane >> 4, cit = lane & 15;
    __hip_bfloat16* sc = (__hip_bfloat16*)scoreT;
    for (int tn = 0; tn < 4; ++tn) {
        int ig = bn * 128 + wave_n * 64 + tn * 16 + cit;   // column i
        float p = 0.0f;
        for (int tm = 0; tm < 4; ++tm) {
            int ob = bm * 128 + wave_m * 64 + tm * 16 + quad * 4;
            f32x4 c = acc[tm][tn];
            for (int r = 0; r < 4; ++r) {
                float v = c[r];
                p += fabsf(v);
                sc[(size_t)(ob + r) * NPAD + ig] = __float2bfloat16(v);
            }
        }
        p += __shfl_xor(p, 16);
        p += __shfl_xor(p, 32);
        if (quad == 0) atomicAdd(&l1[ig], p);
    }
}

// ---- rcp in place: l1[i] = 1/max(l1[i], eps) ----
__global__ void rcp_kernel(float* __restrict__ l1) {
    int i = blockIdx.x * 256 + threadIdx.x;
    if (i < NPAD) l1[i] = 1.0f / fmaxf(l1[i], 1e-12f);
}

// ---- VmatT[n=b*3+e][i] = rcp[i] * sum_d x[b,i,d]*vw[e,d], bf16, padded i ----
__global__ void build_vmat(const float* __restrict__ x, const float* __restrict__ vw,
                           const float* __restrict__ rcp, short* __restrict__ vmatT) {
    int idx = blockIdx.x * 256 + threadIdx.x;     // b*NPAD + i
    if (idx >= B_SZ * NPAD) return;
    int b = idx / NPAD, i = idx % NPAD;
    __hip_bfloat16* vt = (__hip_bfloat16*)vmatT;
    if (i < N_IN) {
        const float* xp = x + ((size_t)b * N_IN + i) * 3;
        float x0 = xp[0], x1 = xp[1], x2 = xp[2];
        float r = rcp[i];
        for (int e = 0; e < 3; ++e) {
            float v = x0 * vw[e * 3 + 0] + x1 * vw[e * 3 + 1] + x2 * vw[e * 3 + 2];
            vt[(size_t)(b * 3 + e) * NPAD + i] = __float2bfloat16(v * r);
        }
    } else {
        for (int e = 0; e < 3; ++e)
            vt[(size_t)(b * 3 + e) * NPAD + i] = __float2bfloat16(0.0f);
    }
}

// ---- GEMM2: y[o][n] = sum_i score_t[o][i] * VmatT[n][i]; atomicAdd into out ----
// M=5120, N=192, K=5120. Tile 128x64, BK=64, split-K=2. Wave tile 64x32 (2x2 waves).
__launch_bounds__(256)
__global__ void gemm2(const short* __restrict__ scoreT, const short* __restrict__ vmatT,
                      float* __restrict__ out) {
    __shared__ short As[128 * 64];
    __shared__ short Bs[64 * 64];
    const int bm = blockIdx.x;      // o tile (40)
    const int bn = blockIdx.y;      // n tile of 64 (3)
    const int z  = blockIdx.z;      // split-K (2)
    const int tid = threadIdx.x, lane = tid & 63, wid = tid >> 6;
    const int wave_m = wid >> 1, wave_n = wid & 1;
    const int srow = lane >> 3, scol = (lane & 7) * 8;

    f32x4 acc[4][2];
    const f32x4 zf = {0.f, 0.f, 0.f, 0.f};
    for (int a = 0; a < 4; ++a)
        for (int b = 0; b < 2; ++b) acc[a][b] = zf;

    const int kbeg = z * (NPAD / 2), kend = kbeg + (NPAD / 2);
    for (int kb = kbeg; kb < kend; kb += 64) {
        __syncthreads();
        for (int c = 0; c < 4; ++c) {
            int q = wid * 4 + c;
            int row = q * 8 + srow;
            async_copy16(scoreT + (size_t)(bm * 128 + row) * NPAD + kb + scol, As + q * 512);
        }
        for (int c = 0; c < 2; ++c) {
            int q = wid * 2 + c;
            int row = q * 8 + srow;
            async_copy16(vmatT + (size_t)(bn * 64 + row) * NPAD + kb + scol, Bs + q * 512);
        }
        __syncthreads();
        for (int kk = 0; kk < 64; kk += 32) {
            bf16x8 af[4], bf[2];
            int ko = kk + (lane >> 4) * 8;
            for (int t = 0; t < 4; ++t)
                af[t] = *(const bf16x8*)(As + (wave_m * 64 + t * 16 + (lane & 15)) * 64 + ko);
            for (int t = 0; t < 2; ++t)
                bf[t] = *(const bf16x8*)(Bs + (wave_n * 32 + t * 16 + (lane & 15)) * 64 + ko);
            for (int tm = 0; tm < 4; ++tm)
                for (int tn = 0; tn < 2; ++tn)
                    acc[tm][tn] = __builtin_amdgcn_mfma_f32_16x16x32_bf16(
                        af[tm], bf[tn], acc[tm][tn], 0, 0, 0);
        }
    }

    const int quad = lane >> 4, cit = lane & 15;
    for (int tn = 0; tn < 2; ++tn) {
        int n = bn * 64 + wave_n * 32 + tn * 16 + cit;     // < 192
        int b = n / 3, d = n % 3;
        for (int tm = 0; tm < 4; ++tm) {
            int ob = bm * 128 + wave_m * 64 + tm * 16 + quad * 4;
            f32x4 c = acc[tm][tn];
            for (int r = 0; r < 4; ++r) {
                int o = ob + r;
                if (o < N_IN)
                    atomicAdd(out + (size_t)b * (N_IN * 3) + (size_t)o * 3 + d, c[r]);
            }
        }
    }
}

extern "C" void kernel_launch(void* const* d_in, const int* in_sizes, int n_in,
                              void* d_out, int out_size, void* d_ws, size_t ws_size,
                              hipStream_t stream) {
    const float* x  = (const float*)d_in[0];
    const float* kw = (const float*)d_in[1];
    const float* qw = (const float*)d_in[2];
    const float* vw = (const float*)d_in[3];
    float* out = (float*)d_out;

    char* w = (char*)d_ws;
    short* keyb   = (short*)(w + 0);                      // 5120*256*2  = 2,621,440
    short* qtb    = (short*)(w + 2621440);                // 5120*256*2  = 2,621,440
    short* scoreT = (short*)(w + 5242880);                // 5120*5120*2 = 52,428,800
    float* l1     = (float*)(w + 57671680);               // 5120*4      = 20,480
    short* vmatT  = (short*)(w + 57692160);               // 192*5120*2  = 1,966,080
    // total: 59,658,240 bytes

    zero_kernel<<<(OUT_ELEMS + 255) / 256, 256, 0, stream>>>(out, l1);
    conv_key<<<(NPAD * H_DIM) / 256, 256, 0, stream>>>(kw, keyb);
    conv_qt<<<(NPAD * H_DIM) / 256, 256, 0, stream>>>(qw, qtb);
    gemm1<<<dim3(NPAD / 128, NPAD / 128), 256, 0, stream>>>(qtb, keyb, scoreT, l1);
    rcp_kernel<<<NPAD / 256, 256, 0, stream>>>(l1);
    build_vmat<<<(B_SZ * NPAD) / 256, 256, 0, stream>>>(x, vw, l1, vmatT);
    gemm2<<<dim3(NPAD / 128, 3, 2), 256, 0, stream>>>(scoreT, vmatT, out);
}